// Round 8
// baseline (1577.143 us; speedup 1.0000x reference)
//
#include <hip/hip_runtime.h>
#include <math.h>
#include <float.h>

// ---- problem constants (N=1, C=1, 256x256, sigma scalar) ----
constexpr int IMG  = 256;            // H = W
constexpr int PADR = 21;             // p//2 + w//2 = 3 + 18
constexpr int PDIM = IMG + 2*PADR;   // 298
constexpr int XDIM = PDIM - 7 + 1;   // 292  (unfold spatial dim)
constexpr int LTOT = XDIM * XDIM;    // 85264
constexpr int WSZ  = 37;             // search window
constexpr int INC  = 18;             // WSZ/2
constexpr int ST   = 4;              // stride
constexpr int GDIM = 64;             // query grid per dim (256/4)
constexpr int NBLK = GDIM * GDIM;    // 4096
constexpr int PS   = 7;              // patch size
constexpr int PP   = 49;             // patch pixels
constexpr int MM1  = 18;
constexpr int MM2  = 55;
constexpr int RG   = 43;             // search region = 2*INC + PS
constexpr int NOFF = WSZ * WSZ;      // 1369
constexpr int UCAP = (NOFF + 63) / 64;  // 22 dist values cached per lane
constexpr int TDIM = 43;             // per-group output footprint (37 + 7 - 1)
constexpr int TSZ  = TDIM * TDIM;    // 1849
constexpr int SLABSTRIDE = 2 * TSZ;  // num + weight channels per group

// ---------------- reflect pad: src (IMG x IMG) -> dst (PDIM x PDIM) ----------
__global__ void pad_reflect(const float* __restrict__ src, float* __restrict__ dst)
{
    int idx = blockIdx.x * 256 + threadIdx.x;
    if (idx >= PDIM * PDIM) return;
    int y = idx / PDIM, x = idx % PDIM;
    int oy = y - PADR; oy = (oy < 0) ? -oy : ((oy >= IMG) ? 2*(IMG-1) - oy : oy);
    int ox = x - PADR; ox = (ox < 0) ? -ox : ((ox >= IMG) ? 2*(IMG-1) - ox : ox);
    dst[idx] = src[oy * IMG + ox];
}

// ---------------- block matching: one workgroup per query block -------------
__global__ __launch_bounds__(256) void block_match(const float* __restrict__ pad,
                                                   int* __restrict__ pos, int m)
{
    __shared__ float reg[RG][RG + 1];
    __shared__ float dist[NOFF];

    const int gi = blockIdx.y, gj = blockIdx.x;
    const int tid = threadIdx.x;
    const int r0 = ST * gi, c0 = ST * gj;

    for (int t = tid; t < RG * RG; t += 256) {
        int r = t / RG, c = t % RG;
        reg[r][c] = pad[(r0 + r) * PDIM + (c0 + c)];
    }
    __syncthreads();

    float q[PP];
#pragma unroll
    for (int i = 0; i < PS; i++)
#pragma unroll
        for (int j = 0; j < PS; j++)
            q[i * PS + j] = reg[INC + i][INC + j];

    for (int o = tid; o < NOFF; o += 256) {
        int oi = o / WSZ, oj = o % WSZ;
        float s = 0.f;
#pragma unroll
        for (int i = 0; i < PS; i++)
#pragma unroll
            for (int j = 0; j < PS; j++) {
                float d = reg[oi + i][oj + j] - q[i * PS + j];
                s += d * d;
            }
        dist[o] = (o == INC * WSZ + INC) ? -1.0f : s;   // self match sentinel
    }
    __syncthreads();

    if (tid >= 64) return;        // selection runs on wave 0 only
    const int lane = tid;

    float dv[UCAP];
#pragma unroll
    for (int u = 0; u < UCAP; u++) {
        int o = lane + (u << 6);
        dv[u] = (o < NOFF) ? dist[o] : FLT_MAX;
    }

    const int blk = gi * GDIM + gj;
    for (int sel = 0; sel < m; sel++) {
        float bv = dv[0]; int bo = lane;
#pragma unroll
        for (int u = 1; u < UCAP; u++) {
            int o = lane + (u << 6);
            if (dv[u] < bv) { bv = dv[u]; bo = o; }
        }
#pragma unroll
        for (int d = 1; d < 64; d <<= 1) {
            float ov = __shfl_xor(bv, d);
            int   oo = __shfl_xor(bo, d);
            if (ov < bv || (ov == bv && oo < bo)) { bv = ov; bo = oo; }
        }
        if (lane == 0) {
            int oi = bo / WSZ, oj = bo % WSZ;
            pos[blk * m + sel] = (oi + ST * gi) * XDIM + (oj + ST * gj);
        }
#pragma unroll
        for (int u = 0; u < UCAP; u++)
            if (bo == lane + (u << 6)) dv[u] = FLT_MAX;
    }
}

// ---------------- denoise + scatter: one workgroup per group ----------------
// M = Gram(S) (+ c*I if ADDC). Inversion: symmetric sweep, column-per-lane in
// wave-0 registers; runtime k-loop, pivot column broadcast via small LDS.
// Waves 1-3 gather Yt concurrently with the sweep (Ssh/Yt share one buffer).
// theta = I - c*Minv; Xh = Y - c*(Minv Y); w_k = 1/rowsum(theta^2).
// SLAB: scatter via global atomics into the PRIVATE per-group slab region
// (single-XCD lines -> L2-local RMW, write-back once). No LDS tile.
template<int M_, bool ADDC, bool SLAB>
__global__ __launch_bounds__(256, 5) void denoise_scatter(
    const float* __restrict__ padY, const float* __restrict__ padS,
    const int* __restrict__ pos, const float* __restrict__ sigma_p,
    float* __restrict__ dst, float* __restrict__ Wacc)
{
    constexpr int MP  = (M_ + 4) & ~3;       // Msh row stride: 56 / 20
    constexpr int SS  = 52;                  // Ssh row stride (13*16B, zero-padded)
    constexpr int YS  = 60;                  // Yt  row stride (15*16B, conflict-free)
    constexpr int TRI = M_ * (M_ + 1) / 2;
    constexpr int UNF = (M_ * SS > PP * YS) ? M_ * SS : PP * YS;

    __shared__ __align__(16) float SY [UNF];       // Ssh (gather/Gram) then Yt
    __shared__ __align__(16) float Msh[M_ * MP];   // Gram -> Minv, pad cols zero
    __shared__ float pcol[M_];
    __shared__ float wsh[M_];
    __shared__ int   posh[M_];

    float* Ssh = SY;
    float* Yt  = SY;

    const int tid = threadIdx.x;
    const int blk = blockIdx.x;
    const float sg = *sigma_p;
    const float c  = (float)PP * sg * sg;

    if (tid < M_) posh[tid] = pos[blk * M_ + tid];
    __syncthreads();

    // gather S: Ssh row-major (stride-1 LDS writes), cols 49..51 zeroed
    for (int t = tid; t < M_ * SS; t += 256) {
        int k = t / SS, qq = t - (t / SS) * SS;
        float v = 0.f;
        if (qq < PP) {
            int p_ = posh[k];
            int a = p_ / XDIM, b = p_ - (p_ / XDIM) * XDIM;
            v = padS[(a + qq / PS) * PDIM + (b + qq % PS)];
        }
        Ssh[t] = v;
    }
    __syncthreads();

    // Gram, triangle-mapped (full waves), float4 over q; write lower triangle
    for (int t = tid; t < TRI; t += 256) {
        int i = (int)((sqrtf((float)(8 * t + 1)) - 1.f) * 0.5f);
        if ((i + 1) * (i + 2) / 2 <= t) i++;
        else if (i * (i + 1) / 2 > t) i--;
        int j = t - i * (i + 1) / 2;           // j <= i
        const float4* Si = (const float4*)&Ssh[i * SS];
        const float4* Sj = (const float4*)&Ssh[j * SS];
        float acc = 0.f;
#pragma unroll
        for (int cch = 0; cch < SS / 4; cch++) {
            float4 a4 = Si[cch], b4 = Sj[cch];
            acc += a4.x * b4.x + a4.y * b4.y + a4.z * b4.z + a4.w * b4.w;
        }
        if (ADDC && i == j) acc += c;
        Msh[i * MP + j] = acc;
    }
    __syncthreads();

    // ---- wave0: sweep inversion (runtime k loop, compact code) ----
    // ---- waves1-3: gather Yt (overwrites Ssh), overlapped with the sweep ----
    if (tid < 64) {
        const int j = (tid < M_) ? tid : (M_ - 1);   // clamp extra lanes
        float col[M_];
#pragma unroll
        for (int i = 0; i < M_; i++)
            col[i] = Msh[(i >= j) ? (i * MP + j) : (j * MP + i)];

#pragma unroll 1
        for (int k = 0; k < M_; k++) {
            if (tid == k) {
#pragma unroll
                for (int i = 0; i < M_; i++) pcol[i] = col[i];
            }
            float piv = pcol[j];          // same-wave DS ordering
            float d   = pcol[k];
            d = (fabsf(d) > 1e-30f) ? d : 1e-30f;
            float dinv = 1.0f / d;
            bool  isk  = (j == k);
            float f    = isk ? (1.0f - dinv) : (piv * dinv);
            float fix  = isk ? (-dinv)       : (piv * dinv);
            float negf = -f;
#pragma unroll
            for (int i = 0; i < M_; i++) {
                float b   = __int_as_float(
                    __builtin_amdgcn_readlane(__float_as_int(col[i]), k));
                float upd = fmaf(b, negf, col[i]);
                col[i] = (i == k) ? fix : upd;
            }
        }
        // col = column j of -M^{-1}
        if (tid < M_) {
            float s = 0.f;
#pragma unroll
            for (int i = 0; i < M_; i++) {
                float th = fmaf(c, col[i], (i == j) ? 1.f : 0.f);  // I - c*Minv
                s = fmaf(th, th, s);
            }
            wsh[j] = 1.0f / s;
#pragma unroll
            for (int i = 0; i < M_; i++)
                Msh[i * MP + j] = -col[i];                          // Minv
        } else if (tid < MP) {
#pragma unroll
            for (int i = 0; i < M_; i++)
                Msh[i * MP + tid] = 0.f;                            // zero pad cols
        }
    } else {
        const int t0 = tid - 64;
        // gather Yt transposed, cols M_..MP-1 zeroed (for padded float4 dots)
        for (int t = t0; t < PP * MP; t += 192) {
            int qq = t / MP, k = t - (t / MP) * MP;
            float v = 0.f;
            if (k < M_) {
                int p_ = posh[k];
                int a = p_ / XDIM, b = p_ - (p_ / XDIM) * XDIM;
                v = padY[(a + qq / PS) * PDIM + (b + qq % PS)];
            }
            Yt[qq * YS + k] = v;
        }
    }
    __syncthreads();

    // ---- Z = Minv*Y, split-half 2x2 register-tiled, fused weighted scatter --
    constexpr int KP = (M_ + 1) / 2;
    constexpr int QP = (PP + 1) / 2;                 // 25
    const int r0 = ST * (blk >> 6), c0 = ST * (blk & (GDIM - 1));
    float* slab = SLAB ? (dst + (size_t)blk * SLABSTRIDE) : dst;
    for (int t = tid; t < KP * QP; t += 256) {
        int kp = t / QP, qp = t - (t / QP) * QP;
        int k0 = kp,  k1 = kp + KP;                  // per-lane stride 1 row
        int qq0 = qp, qq1 = qp + QP;
        bool k1v = (k1 < M_), q1v = (qq1 < PP);
        int k1c  = k1v ? k1 : k0;
        int qq1c = q1v ? qq1 : qq0;
        const float4* G0 = (const float4*)&Msh[k0  * MP];
        const float4* G1 = (const float4*)&Msh[k1c * MP];
        const float4* Y0 = (const float4*)&Yt [qq0  * YS];
        const float4* Y1 = (const float4*)&Yt [qq1c * YS];
        float z00 = 0.f, z01 = 0.f, z10 = 0.f, z11 = 0.f;
#pragma unroll
        for (int cch = 0; cch < MP / 4; cch++) {
            float4 g0 = G0[cch], g1 = G1[cch], y0 = Y0[cch], y1 = Y1[cch];
            z00 += g0.x*y0.x + g0.y*y0.y + g0.z*y0.z + g0.w*y0.w;
            z01 += g0.x*y1.x + g0.y*y1.y + g0.z*y1.z + g0.w*y1.w;
            z10 += g1.x*y0.x + g1.y*y0.y + g1.z*y0.z + g1.w*y0.w;
            z11 += g1.x*y1.x + g1.y*y1.y + g1.z*y1.z + g1.w*y1.w;
        }
        float w0 = wsh[k0], w1 = k1v ? wsh[k1] : 0.f;
        int p0 = posh[k0], p1 = posh[k1c];
        float xh00 = (Yt[qq0  * YS + k0 ] - c * z00) * w0;
        float xh01 = (Yt[qq1c * YS + k0 ] - c * z01) * w0;
        float xh10 = (Yt[qq0  * YS + k1c] - c * z10) * w1;
        float xh11 = (Yt[qq1c * YS + k1c] - c * z11) * w1;
        int a0 = p0 / XDIM, b0 = p0 - (p0 / XDIM) * XDIM;
        int a1 = p1 / XDIM, b1 = p1 - (p1 / XDIM) * XDIM;
        int i0 = qq0 / PS,  j0 = qq0 - i0 * PS;
        int i1 = qq1c / PS, j1 = qq1c - i1 * PS;
        if (SLAB) {
            int u0 = a0 - r0, v0 = b0 - c0, u1 = a1 - r0, v1 = b1 - c0;
            int l00 = (u0 + i0) * TDIM + v0 + j0;
            int l10 = (u1 + i0) * TDIM + v1 + j0;
            atomicAdd(&slab[l00], xh00); atomicAdd(&slab[TSZ + l00], w0);
            if (k1v) { atomicAdd(&slab[l10], xh10); atomicAdd(&slab[TSZ + l10], w1); }
            if (q1v) {
                int l01 = (u0 + i1) * TDIM + v0 + j1;
                int l11 = (u1 + i1) * TDIM + v1 + j1;
                atomicAdd(&slab[l01], xh01); atomicAdd(&slab[TSZ + l01], w0);
                if (k1v) { atomicAdd(&slab[l11], xh11); atomicAdd(&slab[TSZ + l11], w1); }
            }
        } else {
            atomicAdd(&slab[qq0 * LTOT + p0], xh00);
            if (q1v) atomicAdd(&slab[qq1 * LTOT + p0], xh01);
            if (k1v) {
                atomicAdd(&slab[qq0 * LTOT + p1], xh10);
                if (q1v) atomicAdd(&slab[qq1 * LTOT + p1], xh11);
            }
        }
    }
    if (!SLAB) {
        for (int t = tid; t < M_; t += 256)
            atomicAdd(&Wacc[posh[t]], wsh[t]);
    }
}

// ---------------- slab fold: gather <=11x11 group tiles, divide, crop -------
__global__ void fold_slab(const float* __restrict__ slab, float* __restrict__ out)
{
    int idx = blockIdx.x * 256 + threadIdx.x;
    if (idx >= IMG * IMG) return;
    int y = (idx >> 8) + PADR, x = (idx & 255) + PADR;   // padded coords
    int qy = y >> 2, ry = y & 3;
    int qx = x >> 2, rx = x & 3;
    float num = 0.f, den = 0.f;
    for (int di = 0; di < 11; di++) {
        int gi = qy - di;
        int li = 4 * di + ry;
        if ((unsigned)gi > (unsigned)(GDIM - 1) || li >= TDIM) continue;
        for (int dj = 0; dj < 11; dj++) {
            int gj = qx - dj;
            int lj = 4 * dj + rx;
            if ((unsigned)gj > (unsigned)(GDIM - 1) || lj >= TDIM) continue;
            const float* s = slab + (size_t)((gi << 6) + gj) * SLABSTRIDE + li * TDIM + lj;
            num += s[0];
            den += s[TSZ];
        }
    }
    out[idx] = num / den;
}

// ---------------- fallback fold (49-tap over planes) + normalize + crop -----
__global__ void fold_norm(const float* __restrict__ Xsum, const float* __restrict__ Wacc,
                          float* __restrict__ out)
{
    int idx = blockIdx.x * 256 + threadIdx.x;
    if (idx >= IMG * IMG) return;
    int y0 = idx / IMG, x0 = idx % IMG;
    int y = y0 + PADR, x = x0 + PADR;
    float num = 0.f, den = 0.f;
#pragma unroll
    for (int i = 0; i < PS; i++)
#pragma unroll
        for (int j = 0; j < PS; j++) {
            int a = y - i, b = x - j;
            num += Xsum[(i * PS + j) * LTOT + a * XDIM + b];
            den += Wacc[a * XDIM + b];
        }
    out[idx] = num / den;
}

extern "C" void kernel_launch(void* const* d_in, const int* in_sizes, int n_in,
                              void* d_out, int out_size, void* d_ws, size_t ws_size,
                              hipStream_t stream)
{
    const float* input = (const float*)d_in[0];
    const float* sigma = (const float*)d_in[1];
    float* out = (float*)d_out;

    char* ws = (char*)d_ws;
    float* padY = (float*)ws; ws += (size_t)PDIM * PDIM * 4;
    float* padX = (float*)ws; ws += (size_t)PDIM * PDIM * 4;
    float* den1 = (float*)ws; ws += (size_t)IMG * IMG * 4;
    int*   pos  = (int*)ws;   ws += (size_t)NBLK * MM2 * 4;
    size_t head = (size_t)(ws - (char*)d_ws);
    size_t slabBytes = (size_t)NBLK * SLABSTRIDE * 4;

    const int padBlocks = (PDIM * PDIM + 255) / 256;
    const int imgBlocks = (IMG * IMG + 255) / 256;

    if (ws_size >= head + slabBytes) {
        // ---- slab path: private-region global atomics, no shared hotspots ----
        float* slab = (float*)ws;

        hipMemsetAsync(slab, 0, slabBytes, stream);
        pad_reflect<<<padBlocks, 256, 0, stream>>>(input, padY);
        block_match<<<dim3(GDIM, GDIM), 256, 0, stream>>>(padY, pos, MM1);
        denoise_scatter<MM1, false, true><<<NBLK, 256, 0, stream>>>(padY, padY, pos, sigma,
                                                                    slab, nullptr);
        fold_slab<<<imgBlocks, 256, 0, stream>>>(slab, den1);

        hipMemsetAsync(slab, 0, slabBytes, stream);
        pad_reflect<<<padBlocks, 256, 0, stream>>>(den1, padX);
        block_match<<<dim3(GDIM, GDIM), 256, 0, stream>>>(padX, pos, MM2);
        denoise_scatter<MM2, true, true><<<NBLK, 256, 0, stream>>>(padY, padX, pos, sigma,
                                                                   slab, nullptr);
        fold_slab<<<imgBlocks, 256, 0, stream>>>(slab, out);
    } else {
        // ---- fallback: global-atomic 49-plane path ----
        float* Xsum = (float*)ws; ws += (size_t)PP * LTOT * 4;
        float* Wacc = (float*)ws;

        hipMemsetAsync(Xsum, 0, (size_t)PP * LTOT * 4, stream);
        hipMemsetAsync(Wacc, 0, (size_t)LTOT * 4, stream);
        pad_reflect<<<padBlocks, 256, 0, stream>>>(input, padY);
        block_match<<<dim3(GDIM, GDIM), 256, 0, stream>>>(padY, pos, MM1);
        denoise_scatter<MM1, false, false><<<NBLK, 256, 0, stream>>>(padY, padY, pos, sigma,
                                                                     Xsum, Wacc);
        fold_norm<<<imgBlocks, 256, 0, stream>>>(Xsum, Wacc, den1);

        pad_reflect<<<padBlocks, 256, 0, stream>>>(den1, padX);
        hipMemsetAsync(Xsum, 0, (size_t)PP * LTOT * 4, stream);
        hipMemsetAsync(Wacc, 0, (size_t)LTOT * 4, stream);
        block_match<<<dim3(GDIM, GDIM), 256, 0, stream>>>(padX, pos, MM2);
        denoise_scatter<MM2, true, false><<<NBLK, 256, 0, stream>>>(padY, padX, pos, sigma,
                                                                    Xsum, Wacc);
        fold_norm<<<imgBlocks, 256, 0, stream>>>(Xsum, Wacc, out);
    }
}